// Round 5
// baseline (291.356 us; speedup 1.0000x reference)
//
#include <hip/hip_runtime.h>
#include <hip/hip_bf16.h>

// Bahdanau additive attention, B=32, L=2048, H=1024, fp32 in/out.
// score_kernel: block = 128 l-rows (shared LDS A-tile) x 512 o-cols (8 waves x 64o),
// wave tile m=4 x n=2 (128l x 64o), K chunked at 256, LDS dbuf, depth-3 B prefetch,
// two-batch staging (issue-early/write-late). Two o-half blocks -> pscore partials.

#define B_ 32
#define L_ 2048
#define H_ 1024

typedef __attribute__((ext_vector_type(8))) short bf16x8;   // 8 bf16 = 4 VGPRs
typedef __attribute__((ext_vector_type(16))) float f32x16;  // 32x32 MFMA acc
typedef __attribute__((ext_vector_type(4))) float f32x4;

__device__ inline unsigned pk_bf16(float a, float b) {
    unsigned r;
    asm("v_cvt_pk_bf16_f32 %0, %1, %2" : "=v"(r) : "v"(a), "v"(b));
    return r;
}

__device__ inline float fast_tanh(float x) {
    float e = __expf(2.f * x);
    return 1.f - 2.f * __builtin_amdgcn_rcpf(e + 1.f);
}

__device__ inline f32x4 ntload4(const float* p) {
    return __builtin_nontemporal_load((const f32x4*)p);
}

// A-frag slot in LDS: [s 0..15][mblk 0..3][lane-slot 0..63][8 ushort]
__device__ inline int aslot(int s, int m, int lf) {
    return (((s * 4 + m) * 64) + (lf ^ ((s & 3) << 1))) * 8;
}

// ---- kernel 0a: Ua_w -> bf16 B-fragments [s 0..63][nb 0..31][lane][j 0..7]
__global__ void prep_ua(const float* __restrict__ Ua, ushort* __restrict__ Ufrag) {
    int t = blockIdx.x * 256 + threadIdx.x;
    int lane = t & 63;
    int nb   = (t >> 6) & 31;
    int s    = t >> 11;
    int o = nb * 32 + (lane & 31);
    int h = s * 16 + (lane >> 5) * 8;
    const float* src = Ua + o * H_ + h;
    f32x4 f0 = *(const f32x4*)(src);
    f32x4 f1 = *(const f32x4*)(src + 4);
    uint4 pk;
    pk.x = pk_bf16(f0.x, f0.y);
    pk.y = pk_bf16(f0.z, f0.w);
    pk.z = pk_bf16(f1.x, f1.y);
    pk.w = pk_bf16(f1.z, f1.w);
    *(uint4*)(Ufrag + (size_t)t * 8) = pk;
}

// ---- kernel 0b: qbuf[b][o] = query[b]·Wa_w[o] + Wa_b[o] + Ua_b[o]
__global__ void prep_q(const float* __restrict__ query, const float* __restrict__ Wa_w,
                       const float* __restrict__ Wa_b, const float* __restrict__ Ua_b,
                       float* __restrict__ qbuf) {
    int wid  = blockIdx.x * 4 + (threadIdx.x >> 6);
    int lane = threadIdx.x & 63;
    int b = wid >> 10, o = wid & 1023;
    const float* qrow = query + b * H_;
    const float* wrow = Wa_w + o * H_;
    float acc = 0.f;
    #pragma unroll
    for (int i = 0; i < 16; ++i) {
        int h = i * 64 + lane;
        acc += qrow[h] * wrow[h];
    }
    #pragma unroll
    for (int m = 1; m < 64; m <<= 1) acc += __shfl_xor(acc, m);
    if (lane == 0) qbuf[b * H_ + o] = acc + Wa_b[o] + Ua_b[o];
}

// ---- kernel 1: fused k-proj MFMA + tanh + va-dot -> pscore[oh][b][l] (partial over o-half)
__launch_bounds__(512, 2)
__global__ void score_kernel(const float* __restrict__ key, const ushort* __restrict__ Ufrag,
                             const float* __restrict__ qbuf, const float* __restrict__ va_w,
                             float* __restrict__ pscore) {
    __shared__ ushort Alds[2][16 * 4 * 64 * 8];   // 2 x 64 KB
    __shared__ float s_part[8][128];

    int bid = blockIdx.x;              // 1024 = 32 b * 16 l-tiles * 2 o-halves
    int oh = bid & 1;
    int lt = (bid >> 1) & 15;
    int b  = bid >> 5;
    int l0 = lt * 128;
    int tid = threadIdx.x;
    int w = tid >> 6, lane = tid & 63;

    // staging coords: thread covers row r, cols {c0 + j*32 .. +7} for j=0..7
    int r    = tid >> 2;               // 0..127
    int mblk = r >> 5;
    int rr   = r & 31;
    int c0   = (tid & 3) * 8;          // 0,8,16,24
    const float* krow = key + ((size_t)b * L_ + (l0 + r)) * H_;

    // ---- prologue: stage chunk 0 into buf 0
    {
        #pragma unroll
        for (int j = 0; j < 8; ++j) {
            int col = c0 + j * 32;
            f32x4 f0 = ntload4(krow + col);
            f32x4 f1 = ntload4(krow + col + 4);
            int s  = col >> 4;
            int p  = (col >> 3) & 1;
            int lf = p * 32 + rr;
            uint4 pk;
            pk.x = pk_bf16(f0.x, f0.y);
            pk.y = pk_bf16(f0.z, f0.w);
            pk.z = pk_bf16(f1.x, f1.y);
            pk.w = pk_bf16(f1.z, f1.w);
            *(uint4*)&Alds[0][aslot(s, mblk, lf)] = pk;
        }
    }

    int nb0 = oh * 16 + w * 2;                     // wave's 2 o-blocks (64 cols)
    const ushort* Uw = Ufrag + ((size_t)nb0 * 64 + lane) * 8;

    f32x16 acc[4][2] = {};
    bf16x8 bb[4][2];                               // 4 static prefetch banks
    #pragma unroll
    for (int k = 0; k < 3; ++k)
        #pragma unroll
        for (int ni = 0; ni < 2; ++ni)
            bb[k][ni] = *(const bf16x8*)(Uw + (size_t)k * 16384 + ni * 512);
    __syncthreads();

    for (int kc = 0; kc < 4; ++kc) {
        int cur = kc & 1;
        int nxt = cur ^ 1;
        f32x4 ld[8];                               // staging batch (8 x f32x4)
        if (kc < 3) {                              // issue batch 0 (next chunk, cols 0..127)
            #pragma unroll
            for (int j = 0; j < 4; ++j) {
                int col = (kc + 1) * 256 + c0 + j * 32;
                ld[2*j]   = ntload4(krow + col);
                ld[2*j+1] = ntload4(krow + col + 4);
            }
        }
        #pragma unroll
        for (int s = 0; s < 16; ++s) {
            bf16x8 a0 = *(const bf16x8*)&Alds[cur][aslot(s, 0, lane)];
            bf16x8 a1 = *(const bf16x8*)&Alds[cur][aslot(s, 1, lane)];
            bf16x8 a2 = *(const bf16x8*)&Alds[cur][aslot(s, 2, lane)];
            bf16x8 a3 = *(const bf16x8*)&Alds[cur][aslot(s, 3, lane)];
            int gp = (kc * 16 + s + 3) & 63;       // depth-3 prefetch
            #pragma unroll
            for (int ni = 0; ni < 2; ++ni)
                bb[(s + 3) & 3][ni] = *(const bf16x8*)(Uw + (size_t)gp * 16384 + ni * 512);
            acc[0][0] = __builtin_amdgcn_mfma_f32_32x32x16_bf16(a0, bb[s & 3][0], acc[0][0], 0, 0, 0);
            acc[1][0] = __builtin_amdgcn_mfma_f32_32x32x16_bf16(a1, bb[s & 3][0], acc[1][0], 0, 0, 0);
            acc[2][0] = __builtin_amdgcn_mfma_f32_32x32x16_bf16(a2, bb[s & 3][0], acc[2][0], 0, 0, 0);
            acc[3][0] = __builtin_amdgcn_mfma_f32_32x32x16_bf16(a3, bb[s & 3][0], acc[3][0], 0, 0, 0);
            acc[0][1] = __builtin_amdgcn_mfma_f32_32x32x16_bf16(a0, bb[s & 3][1], acc[0][1], 0, 0, 0);
            acc[1][1] = __builtin_amdgcn_mfma_f32_32x32x16_bf16(a1, bb[s & 3][1], acc[1][1], 0, 0, 0);
            acc[2][1] = __builtin_amdgcn_mfma_f32_32x32x16_bf16(a2, bb[s & 3][1], acc[2][1], 0, 0, 0);
            acc[3][1] = __builtin_amdgcn_mfma_f32_32x32x16_bf16(a3, bb[s & 3][1], acc[3][1], 0, 0, 0);
            if (s == 7 && kc < 3) {
                // write batch 0 to nxt buffer, then issue batch 1 (cols 128..255)
                #pragma unroll
                for (int j = 0; j < 4; ++j) {
                    int col = c0 + j * 32;
                    int ss = col >> 4, p = (col >> 3) & 1;
                    int lf = p * 32 + rr;
                    uint4 pk;
                    pk.x = pk_bf16(ld[2*j].x,   ld[2*j].y);
                    pk.y = pk_bf16(ld[2*j].z,   ld[2*j].w);
                    pk.z = pk_bf16(ld[2*j+1].x, ld[2*j+1].y);
                    pk.w = pk_bf16(ld[2*j+1].z, ld[2*j+1].w);
                    *(uint4*)&Alds[nxt][aslot(ss, mblk, lf)] = pk;
                }
                #pragma unroll
                for (int j = 0; j < 4; ++j) {
                    int col = (kc + 1) * 256 + 128 + c0 + j * 32;
                    ld[2*j]   = ntload4(krow + col);
                    ld[2*j+1] = ntload4(krow + col + 4);
                }
            }
        }
        if (kc < 3) {
            #pragma unroll
            for (int j = 0; j < 4; ++j) {
                int col = 128 + c0 + j * 32;
                int ss = col >> 4, p = (col >> 3) & 1;
                int lf = p * 32 + rr;
                uint4 pk;
                pk.x = pk_bf16(ld[2*j].x,   ld[2*j].y);
                pk.y = pk_bf16(ld[2*j].z,   ld[2*j].w);
                pk.z = pk_bf16(ld[2*j+1].x, ld[2*j+1].y);
                pk.w = pk_bf16(ld[2*j+1].z, ld[2*j+1].w);
                *(uint4*)&Alds[nxt][aslot(ss, mblk, lf)] = pk;
            }
            __syncthreads();
        }
    }

    // ---- epilogue: rowsum over this wave's 64 o-cols; C/D: col=lane&31, row=(rg&3)+8*(rg>>2)+4*(lane>>5)
    #pragma unroll
    for (int mi = 0; mi < 4; ++mi) {
        float rowsum[16];
        #pragma unroll
        for (int rg = 0; rg < 16; ++rg) rowsum[rg] = 0.f;
        #pragma unroll
        for (int ni = 0; ni < 2; ++ni) {
            int col = (nb0 + ni) * 32 + (lane & 31);
            float qv  = qbuf[b * H_ + col];
            float vav = va_w[col];
            #pragma unroll
            for (int rg = 0; rg < 16; ++rg)
                rowsum[rg] += vav * fast_tanh(qv + acc[mi][ni][rg]);
        }
        #pragma unroll
        for (int rg = 0; rg < 16; ++rg) {
            float v = rowsum[rg];
            v += __shfl_xor(v, 1);  v += __shfl_xor(v, 2);  v += __shfl_xor(v, 4);
            v += __shfl_xor(v, 8);  v += __shfl_xor(v, 16);
            if ((lane & 31) == 0) {
                int row = mi * 32 + (rg & 3) + 8 * (rg >> 2) + 4 * (lane >> 5);
                s_part[w][row] = v;
            }
        }
    }
    __syncthreads();
    if (tid < 128) {
        float s = 0.f;
        #pragma unroll
        for (int ww = 0; ww < 8; ++ww) s += s_part[ww][tid];
        pscore[((size_t)oh * B_ + b) * L_ + l0 + tid] = s;
    }
}

// ---- kernel 2: combine o-half partials + bias + mask + softmax -> attn [B][L]
__global__ void softmax_kernel(const float* __restrict__ pscore, const float* __restrict__ va_b,
                               const int* __restrict__ mask, float* __restrict__ attn) {
    __shared__ float red[16];
    int b = blockIdx.x;
    int tid = threadIdx.x;    // 256
    float vab = va_b[0];
    float v[8];
    float mx = -3e38f;
    #pragma unroll
    for (int i = 0; i < 8; ++i) {
        int l = tid + i * 256;
        float s = pscore[b * L_ + l] + pscore[(size_t)B_ * L_ + b * L_ + l] + vab;
        int m = mask[b * L_ + l];
        v[i] = (m == 0) ? -1e10f : s;
        mx = fmaxf(mx, v[i]);
    }
    #pragma unroll
    for (int m = 1; m < 64; m <<= 1) mx = fmaxf(mx, __shfl_xor(mx, m));
    if ((tid & 63) == 0) red[tid >> 6] = mx;
    __syncthreads();
    mx = fmaxf(fmaxf(red[0], red[1]), fmaxf(red[2], red[3]));
    float sum = 0.f;
    #pragma unroll
    for (int i = 0; i < 8; ++i) { v[i] = __expf(v[i] - mx); sum += v[i]; }
    #pragma unroll
    for (int m = 1; m < 64; m <<= 1) sum += __shfl_xor(sum, m);
    if ((tid & 63) == 0) red[8 + (tid >> 6)] = sum;
    __syncthreads();
    sum = red[8] + red[9] + red[10] + red[11];
    float inv = 1.f / sum;
    #pragma unroll
    for (int i = 0; i < 8; ++i) attn[b * L_ + tid + i * 256] = v[i] * inv;
}

// ---- kernel 3: partial context over 128-l chunks -> partial[b*16+ch][1024]
__global__ void context_kernel(const float* __restrict__ attn, const float* __restrict__ value,
                               float* __restrict__ partial) {
    int bid = blockIdx.x;            // 512 = 32 b * 16 chunks
    int b = bid >> 4, ch = bid & 15;
    int l0 = ch * 128;
    int tid = threadIdx.x;           // 256
    f32x4 acc = {0.f, 0.f, 0.f, 0.f};
    const float* vbase = value + ((size_t)b * L_ + l0) * H_ + tid * 4;
    const float* arow  = attn + b * L_ + l0;
    for (int l = 0; l < 128; ++l) {
        float a = arow[l];
        f32x4 vv = *(const f32x4*)(vbase + (size_t)l * H_);
        acc.x += a * vv.x; acc.y += a * vv.y; acc.z += a * vv.z; acc.w += a * vv.w;
    }
    *(f32x4*)(partial + (size_t)bid * H_ + tid * 4) = acc;
}

// ---- kernel 4: reduce 16 partials -> out [B][1][H]
__global__ void reduce_kernel(const float* __restrict__ partial, float* __restrict__ out) {
    int t = blockIdx.x * 256 + threadIdx.x;   // 32768
    int b = t >> 10, h = t & 1023;
    float s = 0.f;
    #pragma unroll
    for (int c = 0; c < 16; ++c) s += partial[(size_t)(b * 16 + c) * H_ + h];
    out[t] = s;
}

extern "C" void kernel_launch(void* const* d_in, const int* in_sizes, int n_in,
                              void* d_out, int out_size, void* d_ws, size_t ws_size,
                              hipStream_t stream) {
    const float* query = (const float*)d_in[0];
    const float* key   = (const float*)d_in[1];
    const float* value = (const float*)d_in[2];
    const int*   mask  = (const int*)d_in[3];
    const float* Wa_w  = (const float*)d_in[4];
    const float* Wa_b  = (const float*)d_in[5];
    const float* Ua_w  = (const float*)d_in[6];
    const float* Ua_b  = (const float*)d_in[7];
    const float* va_w  = (const float*)d_in[8];
    const float* va_b  = (const float*)d_in[9];
    float* out = (float*)d_out;

    char* ws = (char*)d_ws;
    ushort* Ufrag    = (ushort*)ws;                                   // 2 MB
    float*  qbuf     = (float*)(ws + (2u << 20));                     // 128 KB
    float*  pscore   = (float*)(ws + (2u << 20) + (128u << 10));      // 512 KB (2 halves)
    float*  attnb    = (float*)(ws + (2u << 20) + (640u << 10));      // 256 KB
    float*  partial  = (float*)(ws + (2u << 20) + (896u << 10));      // 2 MB

    hipLaunchKernelGGL(prep_ua,        dim3(512),  dim3(256), 0, stream, Ua_w, Ufrag);
    hipLaunchKernelGGL(prep_q,         dim3(8192), dim3(256), 0, stream, query, Wa_w, Wa_b, Ua_b, qbuf);
    hipLaunchKernelGGL(score_kernel,   dim3(1024), dim3(512), 0, stream, key, Ufrag, qbuf, va_w, pscore);
    hipLaunchKernelGGL(softmax_kernel, dim3(32),   dim3(256), 0, stream, pscore, va_b, mask, attnb);
    hipLaunchKernelGGL(context_kernel, dim3(512),  dim3(256), 0, stream, attnb, value, partial);
    hipLaunchKernelGGL(reduce_kernel,  dim3(128),  dim3(256), 0, stream, partial, out);
}

// Round 6
// 271.917 us; speedup vs baseline: 1.0715x; 1.0715x over previous
//
#include <hip/hip_runtime.h>
#include <hip/hip_bf16.h>

// Bahdanau additive attention, B=32, L=2048, H=1024, fp32 in/out.
// score_kernel: block = 128 l-rows (shared LDS A-tile) x 512 o-cols (8 waves x 64o),
// wave tile m=4 x n=2, K chunked at 256, LDS dbuf, depth-3 B prefetch.
// o-half sibling blocks are XCD-paired (same d%8) and key loads are cached,
// so the sibling's key read hits L3/L2 instead of HBM.

#define B_ 32
#define L_ 2048
#define H_ 1024

typedef __attribute__((ext_vector_type(8))) short bf16x8;   // 8 bf16 = 4 VGPRs
typedef __attribute__((ext_vector_type(16))) float f32x16;  // 32x32 MFMA acc
typedef __attribute__((ext_vector_type(4))) float f32x4;

__device__ inline unsigned pk_bf16(float a, float b) {
    unsigned r;
    asm("v_cvt_pk_bf16_f32 %0, %1, %2" : "=v"(r) : "v"(a), "v"(b));
    return r;
}

__device__ inline float fast_tanh(float x) {
    float e = __expf(2.f * x);
    return 1.f - 2.f * __builtin_amdgcn_rcpf(e + 1.f);
}

// A-frag slot in LDS: [s 0..15][mblk 0..3][lane-slot 0..63][8 ushort]
__device__ inline int aslot(int s, int m, int lf) {
    return (((s * 4 + m) * 64) + (lf ^ ((s & 3) << 1))) * 8;
}

// ---- kernel 0a: Ua_w -> bf16 B-fragments [s 0..63][nb 0..31][lane][j 0..7]
__global__ void prep_ua(const float* __restrict__ Ua, ushort* __restrict__ Ufrag) {
    int t = blockIdx.x * 256 + threadIdx.x;
    int lane = t & 63;
    int nb   = (t >> 6) & 31;
    int s    = t >> 11;
    int o = nb * 32 + (lane & 31);
    int h = s * 16 + (lane >> 5) * 8;
    const float* src = Ua + o * H_ + h;
    f32x4 f0 = *(const f32x4*)(src);
    f32x4 f1 = *(const f32x4*)(src + 4);
    uint4 pk;
    pk.x = pk_bf16(f0.x, f0.y);
    pk.y = pk_bf16(f0.z, f0.w);
    pk.z = pk_bf16(f1.x, f1.y);
    pk.w = pk_bf16(f1.z, f1.w);
    *(uint4*)(Ufrag + (size_t)t * 8) = pk;
}

// ---- kernel 0b: qbuf[b][o] = query[b]·Wa_w[o] + Wa_b[o] + Ua_b[o]
__global__ void prep_q(const float* __restrict__ query, const float* __restrict__ Wa_w,
                       const float* __restrict__ Wa_b, const float* __restrict__ Ua_b,
                       float* __restrict__ qbuf) {
    int wid  = blockIdx.x * 4 + (threadIdx.x >> 6);
    int lane = threadIdx.x & 63;
    int b = wid >> 10, o = wid & 1023;
    const float* qrow = query + b * H_;
    const float* wrow = Wa_w + o * H_;
    float acc = 0.f;
    #pragma unroll
    for (int i = 0; i < 16; ++i) {
        int h = i * 64 + lane;
        acc += qrow[h] * wrow[h];
    }
    #pragma unroll
    for (int m = 1; m < 64; m <<= 1) acc += __shfl_xor(acc, m);
    if (lane == 0) qbuf[b * H_ + o] = acc + Wa_b[o] + Ua_b[o];
}

// ---- kernel 1: fused k-proj MFMA + tanh + va-dot -> pscore[oh][b][l] (partial over o-half)
__launch_bounds__(512, 2)
__global__ void score_kernel(const float* __restrict__ key, const ushort* __restrict__ Ufrag,
                             const float* __restrict__ qbuf, const float* __restrict__ va_w,
                             float* __restrict__ pscore) {
    __shared__ ushort Alds[2][16 * 4 * 64 * 8];   // 2 x 64 KB
    __shared__ float s_part[8][128];

    // XCD-pair swizzle: both o-halves of a (b,lt) key tile get the same d%8,
    // so they land on the same XCD and share the key tile in that XCD's L2.
    int d  = blockIdx.x;               // 1024
    int p  = (d & 7) | ((d >> 4) << 3);  // pair index 0..511 = 32 b * 16 lt
    int oh = (d >> 3) & 1;
    int b  = p >> 4;
    int lt = p & 15;
    int l0 = lt * 128;
    int tid = threadIdx.x;
    int w = tid >> 6, lane = tid & 63;

    // staging coords: thread covers row r, cols {c0 + j*32 .. +7}
    int r    = tid >> 2;               // 0..127
    int mblk = r >> 5;
    int rr   = r & 31;
    int c0   = (tid & 3) * 8;          // 0,8,16,24
    const float* krow = key + ((size_t)b * L_ + (l0 + r)) * H_;

    // ---- prologue: stage chunk 0 into buf 0 (cached loads: sibling block reuses via L2/L3)
    {
        #pragma unroll
        for (int j = 0; j < 8; ++j) {
            int col = c0 + j * 32;
            f32x4 f0 = *(const f32x4*)(krow + col);
            f32x4 f1 = *(const f32x4*)(krow + col + 4);
            int s  = col >> 4;
            int pp = (col >> 3) & 1;
            int lf = pp * 32 + rr;
            uint4 pk;
            pk.x = pk_bf16(f0.x, f0.y);
            pk.y = pk_bf16(f0.z, f0.w);
            pk.z = pk_bf16(f1.x, f1.y);
            pk.w = pk_bf16(f1.z, f1.w);
            *(uint4*)&Alds[0][aslot(s, mblk, lf)] = pk;
        }
    }

    int nb0 = oh * 16 + w * 2;                     // wave's 2 o-blocks (64 cols)
    const ushort* Uw = Ufrag + ((size_t)nb0 * 64 + lane) * 8;

    f32x16 acc[4][2] = {};
    bf16x8 bb[4][2];                               // 4 static prefetch banks
    #pragma unroll
    for (int k = 0; k < 3; ++k)
        #pragma unroll
        for (int ni = 0; ni < 2; ++ni)
            bb[k][ni] = *(const bf16x8*)(Uw + (size_t)k * 16384 + ni * 512);
    __syncthreads();

    for (int kc = 0; kc < 4; ++kc) {
        int cur = kc & 1;
        int nxt = cur ^ 1;
        f32x4 ld[8];                               // staging batch (8 x f32x4)
        if (kc < 3) {                              // issue batch 0 (next chunk, cols 0..127)
            #pragma unroll
            for (int j = 0; j < 4; ++j) {
                int col = (kc + 1) * 256 + c0 + j * 32;
                ld[2*j]   = *(const f32x4*)(krow + col);
                ld[2*j+1] = *(const f32x4*)(krow + col + 4);
            }
        }
        #pragma unroll
        for (int s = 0; s < 16; ++s) {
            bf16x8 a0 = *(const bf16x8*)&Alds[cur][aslot(s, 0, lane)];
            bf16x8 a1 = *(const bf16x8*)&Alds[cur][aslot(s, 1, lane)];
            bf16x8 a2 = *(const bf16x8*)&Alds[cur][aslot(s, 2, lane)];
            bf16x8 a3 = *(const bf16x8*)&Alds[cur][aslot(s, 3, lane)];
            int gp = (kc * 16 + s + 3) & 63;       // depth-3 prefetch
            #pragma unroll
            for (int ni = 0; ni < 2; ++ni)
                bb[(s + 3) & 3][ni] = *(const bf16x8*)(Uw + (size_t)gp * 16384 + ni * 512);
            acc[0][0] = __builtin_amdgcn_mfma_f32_32x32x16_bf16(a0, bb[s & 3][0], acc[0][0], 0, 0, 0);
            acc[1][0] = __builtin_amdgcn_mfma_f32_32x32x16_bf16(a1, bb[s & 3][0], acc[1][0], 0, 0, 0);
            acc[2][0] = __builtin_amdgcn_mfma_f32_32x32x16_bf16(a2, bb[s & 3][0], acc[2][0], 0, 0, 0);
            acc[3][0] = __builtin_amdgcn_mfma_f32_32x32x16_bf16(a3, bb[s & 3][0], acc[3][0], 0, 0, 0);
            acc[0][1] = __builtin_amdgcn_mfma_f32_32x32x16_bf16(a0, bb[s & 3][1], acc[0][1], 0, 0, 0);
            acc[1][1] = __builtin_amdgcn_mfma_f32_32x32x16_bf16(a1, bb[s & 3][1], acc[1][1], 0, 0, 0);
            acc[2][1] = __builtin_amdgcn_mfma_f32_32x32x16_bf16(a2, bb[s & 3][1], acc[2][1], 0, 0, 0);
            acc[3][1] = __builtin_amdgcn_mfma_f32_32x32x16_bf16(a3, bb[s & 3][1], acc[3][1], 0, 0, 0);
            if (s == 7 && kc < 3) {
                // write batch 0 to nxt buffer, then issue batch 1 (cols 128..255)
                #pragma unroll
                for (int j = 0; j < 4; ++j) {
                    int col = c0 + j * 32;
                    int ss = col >> 4, pp = (col >> 3) & 1;
                    int lf = pp * 32 + rr;
                    uint4 pk;
                    pk.x = pk_bf16(ld[2*j].x,   ld[2*j].y);
                    pk.y = pk_bf16(ld[2*j].z,   ld[2*j].w);
                    pk.z = pk_bf16(ld[2*j+1].x, ld[2*j+1].y);
                    pk.w = pk_bf16(ld[2*j+1].z, ld[2*j+1].w);
                    *(uint4*)&Alds[nxt][aslot(ss, mblk, lf)] = pk;
                }
                #pragma unroll
                for (int j = 0; j < 4; ++j) {
                    int col = (kc + 1) * 256 + 128 + c0 + j * 32;
                    ld[2*j]   = *(const f32x4*)(krow + col);
                    ld[2*j+1] = *(const f32x4*)(krow + col + 4);
                }
            }
        }
        if (kc < 3) {
            #pragma unroll
            for (int j = 0; j < 4; ++j) {
                int col = 128 + c0 + j * 32;
                int ss = col >> 4, pp = (col >> 3) & 1;
                int lf = pp * 32 + rr;
                uint4 pk;
                pk.x = pk_bf16(ld[2*j].x,   ld[2*j].y);
                pk.y = pk_bf16(ld[2*j].z,   ld[2*j].w);
                pk.z = pk_bf16(ld[2*j+1].x, ld[2*j+1].y);
                pk.w = pk_bf16(ld[2*j+1].z, ld[2*j+1].w);
                *(uint4*)&Alds[nxt][aslot(ss, mblk, lf)] = pk;
            }
            __syncthreads();
        }
    }

    // ---- epilogue: rowsum over this wave's 64 o-cols; C/D: col=lane&31, row=(rg&3)+8*(rg>>2)+4*(lane>>5)
    #pragma unroll
    for (int mi = 0; mi < 4; ++mi) {
        float rowsum[16];
        #pragma unroll
        for (int rg = 0; rg < 16; ++rg) rowsum[rg] = 0.f;
        #pragma unroll
        for (int ni = 0; ni < 2; ++ni) {
            int col = (nb0 + ni) * 32 + (lane & 31);
            float qv  = qbuf[b * H_ + col];
            float vav = va_w[col];
            #pragma unroll
            for (int rg = 0; rg < 16; ++rg)
                rowsum[rg] += vav * fast_tanh(qv + acc[mi][ni][rg]);
        }
        #pragma unroll
        for (int rg = 0; rg < 16; ++rg) {
            float v = rowsum[rg];
            v += __shfl_xor(v, 1);  v += __shfl_xor(v, 2);  v += __shfl_xor(v, 4);
            v += __shfl_xor(v, 8);  v += __shfl_xor(v, 16);
            if ((lane & 31) == 0) {
                int row = mi * 32 + (rg & 3) + 8 * (rg >> 2) + 4 * (lane >> 5);
                s_part[w][row] = v;
            }
        }
    }
    __syncthreads();
    if (tid < 128) {
        float s = 0.f;
        #pragma unroll
        for (int ww = 0; ww < 8; ++ww) s += s_part[ww][tid];
        pscore[((size_t)oh * B_ + b) * L_ + l0 + tid] = s;
    }
}

// ---- kernel 2: combine o-half partials + bias + mask + softmax -> attn [B][L]
__global__ void softmax_kernel(const float* __restrict__ pscore, const float* __restrict__ va_b,
                               const int* __restrict__ mask, float* __restrict__ attn) {
    __shared__ float red[16];
    int b = blockIdx.x;
    int tid = threadIdx.x;    // 256
    float vab = va_b[0];
    float v[8];
    float mx = -3e38f;
    #pragma unroll
    for (int i = 0; i < 8; ++i) {
        int l = tid + i * 256;
        float s = pscore[b * L_ + l] + pscore[(size_t)B_ * L_ + b * L_ + l] + vab;
        int m = mask[b * L_ + l];
        v[i] = (m == 0) ? -1e10f : s;
        mx = fmaxf(mx, v[i]);
    }
    #pragma unroll
    for (int m = 1; m < 64; m <<= 1) mx = fmaxf(mx, __shfl_xor(mx, m));
    if ((tid & 63) == 0) red[tid >> 6] = mx;
    __syncthreads();
    mx = fmaxf(fmaxf(red[0], red[1]), fmaxf(red[2], red[3]));
    float sum = 0.f;
    #pragma unroll
    for (int i = 0; i < 8; ++i) { v[i] = __expf(v[i] - mx); sum += v[i]; }
    #pragma unroll
    for (int m = 1; m < 64; m <<= 1) sum += __shfl_xor(sum, m);
    if ((tid & 63) == 0) red[8 + (tid >> 6)] = sum;
    __syncthreads();
    sum = red[8] + red[9] + red[10] + red[11];
    float inv = 1.f / sum;
    #pragma unroll
    for (int i = 0; i < 8; ++i) attn[b * L_ + tid + i * 256] = v[i] * inv;
}

// ---- kernel 3: partial context over 128-l chunks -> partial[b*16+ch][1024]
__global__ void context_kernel(const float* __restrict__ attn, const float* __restrict__ value,
                               float* __restrict__ partial) {
    int bid = blockIdx.x;            // 512 = 32 b * 16 chunks
    int b = bid >> 4, ch = bid & 15;
    int l0 = ch * 128;
    int tid = threadIdx.x;           // 256
    f32x4 acc = {0.f, 0.f, 0.f, 0.f};
    const float* vbase = value + ((size_t)b * L_ + l0) * H_ + tid * 4;
    const float* arow  = attn + b * L_ + l0;
    for (int l = 0; l < 128; ++l) {
        float a = arow[l];
        f32x4 vv = *(const f32x4*)(vbase + (size_t)l * H_);
        acc.x += a * vv.x; acc.y += a * vv.y; acc.z += a * vv.z; acc.w += a * vv.w;
    }
    *(f32x4*)(partial + (size_t)bid * H_ + tid * 4) = acc;
}

// ---- kernel 4: reduce 16 partials -> out [B][1][H]
__global__ void reduce_kernel(const float* __restrict__ partial, float* __restrict__ out) {
    int t = blockIdx.x * 256 + threadIdx.x;   // 32768
    int b = t >> 10, h = t & 1023;
    float s = 0.f;
    #pragma unroll
    for (int c = 0; c < 16; ++c) s += partial[(size_t)(b * 16 + c) * H_ + h];
    out[t] = s;
}

extern "C" void kernel_launch(void* const* d_in, const int* in_sizes, int n_in,
                              void* d_out, int out_size, void* d_ws, size_t ws_size,
                              hipStream_t stream) {
    const float* query = (const float*)d_in[0];
    const float* key   = (const float*)d_in[1];
    const float* value = (const float*)d_in[2];
    const int*   mask  = (const int*)d_in[3];
    const float* Wa_w  = (const float*)d_in[4];
    const float* Wa_b  = (const float*)d_in[5];
    const float* Ua_w  = (const float*)d_in[6];
    const float* Ua_b  = (const float*)d_in[7];
    const float* va_w  = (const float*)d_in[8];
    const float* va_b  = (const float*)d_in[9];
    float* out = (float*)d_out;

    char* ws = (char*)d_ws;
    ushort* Ufrag    = (ushort*)ws;                                   // 2 MB
    float*  qbuf     = (float*)(ws + (2u << 20));                     // 128 KB
    float*  pscore   = (float*)(ws + (2u << 20) + (128u << 10));      // 512 KB (2 halves)
    float*  attnb    = (float*)(ws + (2u << 20) + (640u << 10));      // 256 KB
    float*  partial  = (float*)(ws + (2u << 20) + (896u << 10));      // 2 MB

    hipLaunchKernelGGL(prep_ua,        dim3(512),  dim3(256), 0, stream, Ua_w, Ufrag);
    hipLaunchKernelGGL(prep_q,         dim3(8192), dim3(256), 0, stream, query, Wa_w, Wa_b, Ua_b, qbuf);
    hipLaunchKernelGGL(score_kernel,   dim3(1024), dim3(512), 0, stream, key, Ufrag, qbuf, va_w, pscore);
    hipLaunchKernelGGL(softmax_kernel, dim3(32),   dim3(256), 0, stream, pscore, va_b, mask, attnb);
    hipLaunchKernelGGL(context_kernel, dim3(512),  dim3(256), 0, stream, attnb, value, partial);
    hipLaunchKernelGGL(reduce_kernel,  dim3(128),  dim3(256), 0, stream, partial, out);
}